// Round 6
// baseline (634.293 us; speedup 1.0000x reference)
//
#include <hip/hip_runtime.h>
#include <hip/hip_bf16.h>

#define DIMD 2048
#define NHD 16
#define QLORA 1536
#define KVLORA 512
#define QKD 192
#define BBD 2
#define SSD 2048
#define BSD (BBD*SSD)       // 4096 tokens
#define NCAT 2176           // QLORA + 576 (kv_down) padded to 17*128
#define BHN (BBD*NHD)       // 32 (b,h) pairs
#define EPSF 1.1920929e-07f
#define SCALEF 0.07216878364870322f  // 192^-0.5

typedef __hip_bfloat16 bf16;
typedef __attribute__((ext_vector_type(8))) short short8;
typedef __attribute__((ext_vector_type(4))) float floatx4;

typedef __attribute__((address_space(1))) char as1_char;
typedef __attribute__((address_space(3))) char as3_char;
#define GLD16(g, l) __builtin_amdgcn_global_load_lds((as1_char*)(g), (as3_char*)(l), 16, 0, 0)

// ---------------- block reduction (256 threads = 4 waves) ----------------
__device__ __forceinline__ float block_sum(float x) {
#pragma unroll
  for (int o = 32; o > 0; o >>= 1) x += __shfl_xor(x, o, 64);
  __shared__ float red[4];
  __syncthreads();
  if ((threadIdx.x & 63) == 0) red[threadIdx.x >> 6] = x;
  __syncthreads();
  return red[0] + red[1] + red[2] + red[3];
}

// ---------------- generic bf16 MFMA GEMM with fused epilogues ----------------
// C = A(MxK) * B(NxK)^T + bias.  MODE 0: fp32 out. 1: bf16 out.
// 2: Q-up + rope -> Qh (B,NH,S,192).  3: KV-up split -> Kh nope + kvf V-part.
template<int MODE>
__global__ __launch_bounds__(256)
void gemm_bt(const bf16* __restrict__ A, const bf16* __restrict__ Bm,
             const float* __restrict__ bias, void* __restrict__ C0,
             bf16* __restrict__ C1, const float2* __restrict__ cstab,
             int M, int N, int K, int ldc)
{
  int m0 = blockIdx.y * 128, n0 = blockIdx.x * 128;

  __shared__ __align__(16) bf16 Asm[128 * 32];
  __shared__ __align__(16) bf16 Bsm[128 * 32];

  const int tid  = threadIdx.x;
  const int lane = tid & 63;
  const int wv   = tid >> 6;
  const int wm   = (wv >> 1) << 6;
  const int wn   = (wv & 1) << 6;
  const int fr   = lane & 15;
  const int q8   = (lane >> 4) << 3;

  floatx4 acc[4][4];
#pragma unroll
  for (int i = 0; i < 4; ++i)
#pragma unroll
    for (int j = 0; j < 4; ++j)
      acc[i][j] = (floatx4){0.f, 0.f, 0.f, 0.f};

  for (int k0 = 0; k0 < K; k0 += 32) {
    __syncthreads();
#pragma unroll
    for (int it = 0; it < 2; ++it) {
      int seg = it * 256 + tid;
      int row = seg >> 2, cs = seg & 3;
      GLD16(A  + (long)(m0 + row) * K + k0 + cs * 8, &Asm[(it * 256 + wv * 64) * 8]);
      GLD16(Bm + (long)(n0 + row) * K + k0 + cs * 8, &Bsm[(it * 256 + wv * 64) * 8]);
    }
    __syncthreads();

    short8 fa[4], fb[4];
#pragma unroll
    for (int t = 0; t < 4; ++t) fa[t] = *(const short8*)&Asm[(wm + t * 16 + fr) * 32 + q8];
#pragma unroll
    for (int t = 0; t < 4; ++t) fb[t] = *(const short8*)&Bsm[(wn + t * 16 + fr) * 32 + q8];
#pragma unroll
    for (int i = 0; i < 4; ++i)
#pragma unroll
      for (int j = 0; j < 4; ++j)
        acc[i][j] = __builtin_amdgcn_mfma_f32_16x16x32_bf16(fa[i], fb[j], acc[i][j], 0, 0, 0);
  }

  int rq = (lane >> 4) * 4;
#pragma unroll
  for (int i = 0; i < 4; ++i) {
#pragma unroll
    for (int j = 0; j < 4; ++j) {
      int colb = n0 + wn + j * 16;   // wave-uniform; 16-col group never crosses a head region
      int col = colb + fr;
      float bv = bias ? bias[col] : 0.f;
      if (MODE == 2) {
        int h = colb / 192;
        int dbase = colb - h * 192;
        bool rope = (dbase >= 128);
#pragma unroll
        for (int r = 0; r < 4; ++r) {
          int rowg = m0 + wm + i * 16 + rq + r;
          int s = rowg & (SSD - 1), bb = rowg >> 11;
          float v = acc[i][j][r] + bv;
          float y;
          if (rope) {
            float2 cs = cstab[s * 32 + ((dbase - 128) >> 1) + (fr >> 1)];
            float other = __shfl_xor(v, 1, 64);
            y = (fr & 1) ? (other * cs.y + v * cs.x) : (v * cs.x - other * cs.y);
          } else y = v;
          ((bf16*)C0)[((long)(bb * NHD + h) * SSD + s) * QKD + dbase + fr] = __float2bfloat16(y);
        }
      } else if (MODE == 3) {
        int h = colb >> 8;
        int dbase = colb & 255;
#pragma unroll
        for (int r = 0; r < 4; ++r) {
          int rowg = m0 + wm + i * 16 + rq + r;
          int s = rowg & (SSD - 1), bb = rowg >> 11;
          float v = acc[i][j][r] + bv;
          if (dbase < 128)
            ((bf16*)C0)[((long)(bb * NHD + h) * SSD + s) * QKD + dbase + fr] = __float2bfloat16(v);
          else
            C1[(long)rowg * 2048 + h * 128 + (dbase - 128) + fr] = __float2bfloat16(v);
        }
      } else {
#pragma unroll
        for (int r = 0; r < 4; ++r) {
          int rowg = m0 + wm + i * 16 + rq + r;
          float v = acc[i][j][r] + bv;
          if (MODE == 1)
            ((bf16*)C0)[(long)rowg * ldc + col] = __float2bfloat16(v);
          else
            ((float*)C0)[(long)rowg * ldc + col] = v;
        }
      }
    }
  }
}

// ---------------- fused flash attention (causal), balanced tile pairs ----------------
// 512 blocks x 256 threads. Q-tile 64 rows (4 waves x 16 rows), K-tile 128 cols.
// Block p does tiles {31-p, p}: exactly 17 j-iters each. K staged in LDS (48KB,
// P aliases); V^T fragments read DIRECT from global (coalesced 64B/row, L1/L2-resident).
__global__ __launch_bounds__(256, 2)
void flash_attn(const bf16* __restrict__ Qh, const bf16* __restrict__ Kh,
                const bf16* __restrict__ Vt, bf16* __restrict__ attnall)
{
  const int p = blockIdx.x;        // 0..15
  const int z = blockIdx.y;        // b*NH + h
  const int b = z >> 4, h = z & 15;

  const bf16* Qg = Qh + (long)z * SSD * QKD;
  const bf16* Kg = Kh + (long)z * SSD * QKD;
  const bf16* Vg = Vt + (long)z * 128 * SSD;

  __shared__ __align__(16) bf16 Ksm[6 * 4096];  // 48KB; P and Q-stage alias
  bf16* Psm = Ksm;

  const int tid  = threadIdx.x;
  const int lane = tid & 63;
  const int wv   = tid >> 6;       // 0..3
  const int fr   = lane & 15;
  const int g4   = lane >> 4;
  const int q8   = g4 << 3;

#pragma unroll 1
  for (int t = 0; t < 2; ++t) {
    const int qt = t ? p : 31 - p;   // heavy tile first
    const int q0 = qt * 64;
    const int jmax = qt >> 1;

    __syncthreads();  // prior tile's LDS reads complete
    // --- stage Q (64 x 192) through Ksm, pull fragments to regs ---
#pragma unroll
    for (int c = 0; c < 6; ++c) {
      int row = tid >> 2, cs = tid & 3;
      GLD16(Qg + (long)(q0 + row) * QKD + c * 32 + cs * 8, &Ksm[c * 4096 + wv * 512]);
    }
    __syncthreads();
    short8 qf[6];
#pragma unroll
    for (int c = 0; c < 6; ++c)
      qf[c] = *(const short8*)&Ksm[c * 4096 + (wv * 16 + fr) * 32 + q8];

    floatx4 oacc[8];
#pragma unroll
    for (int n = 0; n < 8; ++n) oacc[n] = (floatx4){0.f, 0.f, 0.f, 0.f};
    float mi[4], li[4];
#pragma unroll
    for (int r = 0; r < 4; ++r) { mi[r] = -1e30f; li[r] = 0.f; }

    for (int j = 0; j <= jmax; ++j) {
      const int jb = j * 128;
      __syncthreads();  // qf reads / prev-iter P reads complete
#pragma unroll
      for (int c = 0; c < 6; ++c)
#pragma unroll
        for (int it = 0; it < 2; ++it) {
          int seg = it * 256 + tid;
          int row = seg >> 2, cs = seg & 3;
          GLD16(Kg + (long)(jb + row) * QKD + c * 32 + cs * 8,
                &Ksm[c * 4096 + it * 2048 + wv * 512]);
        }
      __syncthreads();  // drains vmcnt

      // ---- S = Q K^T : this wave's 16 rows x 128 cols ----
      floatx4 sacc[8];
#pragma unroll
      for (int n = 0; n < 8; ++n) sacc[n] = (floatx4){0.f, 0.f, 0.f, 0.f};
#pragma unroll
      for (int c = 0; c < 6; ++c) {
#pragma unroll
        for (int n = 0; n < 8; ++n) {
          short8 fb = *(const short8*)&Ksm[c * 4096 + (n * 16 + fr) * 32 + q8];
          sacc[n] = __builtin_amdgcn_mfma_f32_16x16x32_bf16(qf[c], fb, sacc[n], 0, 0, 0);
        }
      }

      // ---- online softmax (rows fully inside this wave; 16-lane reductions) ----
      const bool diag = (j == jmax);
#pragma unroll
      for (int r = 0; r < 4; ++r) {
        int rowg = q0 + wv * 16 + g4 * 4 + r;
        float mx = -1e30f;
#pragma unroll
        for (int n = 0; n < 8; ++n) {
          float v = sacc[n][r] * SCALEF;
          if (diag && (jb + n * 16 + fr) > rowg) v = -1e30f;
          sacc[n][r] = v;
          mx = fmaxf(mx, v);
        }
#pragma unroll
        for (int off = 1; off < 16; off <<= 1) mx = fmaxf(mx, __shfl_xor(mx, off, 64));
        float mnew = fmaxf(mi[r], mx);
        float alpha = __expf(mi[r] - mnew);
        mi[r] = mnew;
        float rs = 0.f;
#pragma unroll
        for (int n = 0; n < 8; ++n) {
          float pv = __expf(sacc[n][r] - mnew);
          sacc[n][r] = pv;
          rs += pv;
        }
#pragma unroll
        for (int off = 1; off < 16; off <<= 1) rs += __shfl_xor(rs, off, 64);
        li[r] = li[r] * alpha + rs;
#pragma unroll
        for (int n = 0; n < 8; ++n) oacc[n][r] *= alpha;
      }

      // ---- P -> LDS (C/D layout -> A-operand layout), aliasing dead K region ----
      __syncthreads();  // all waves done reading Ksm fragments
#pragma unroll
      for (int n = 0; n < 8; ++n) {
        int c2 = n >> 1;
        int col = (n & 1) * 16 + fr;
#pragma unroll
        for (int r = 0; r < 4; ++r) {
          int m = wv * 16 + g4 * 4 + r;
          Psm[c2 * 4096 + m * 32 + col] = __float2bfloat16(sacc[n][r]);
        }
      }
      // same-wave write->read ordering via compiler-inserted lgkmcnt

      // ---- O += P V : P from LDS, V^T fragments DIRECT from global ----
#pragma unroll
      for (int c2 = 0; c2 < 4; ++c2) {
        short8 pf = *(const short8*)&Psm[c2 * 4096 + (wv * 16 + fr) * 32 + q8];
#pragma unroll
        for (int dn = 0; dn < 8; ++dn) {
          short8 vf = *(const short8*)(Vg + (long)(dn * 16 + fr) * SSD + jb + c2 * 32 + q8);
          oacc[dn] = __builtin_amdgcn_mfma_f32_16x16x32_bf16(pf, vf, oacc[dn], 0, 0, 0);
        }
      }
    }

    // ---- normalize and write O directly in (B,S,NH*128) layout ----
#pragma unroll
    for (int r = 0; r < 4; ++r) {
      float inv = 1.f / li[r];
      int m = q0 + wv * 16 + g4 * 4 + r;
      bf16* orow = attnall + ((long)(b * SSD + m) * NHD + h) * 128;
#pragma unroll
      for (int dn = 0; dn < 8; ++dn)
        orow[dn * 16 + fr] = __float2bfloat16(oacc[dn][r] * inv);
    }
  }
}

// ---------------- fused fp32 -> bf16 converts (float4-vectorized) ----------------
__device__ __forceinline__ void cvt4(const float* __restrict__ s, bf16* __restrict__ d,
                                     long se, long de) {
  float4 v = *(const float4*)(s + se);
  union { bf16 h[4]; uint2 u; } o;
  o.h[0] = __float2bfloat16(v.x); o.h[1] = __float2bfloat16(v.y);
  o.h[2] = __float2bfloat16(v.z); o.h[3] = __float2bfloat16(v.w);
  *(uint2*)(d + de) = o.u;
}

#define NX4   ((long)BSD * DIMD / 4)
#define NCAT4 ((long)NCAT * DIMD / 4)
#define NQU4  ((long)3072 * QLORA / 4)
#define NKVU4 ((long)4096 * KVLORA / 4)
#define NWO4  ((long)DIMD * 2048 / 4)

__global__ __launch_bounds__(256)
void cvt_all(const float* __restrict__ x, const float* __restrict__ wqd,
             const float* __restrict__ wkvd, const float* __restrict__ wqu,
             const float* __restrict__ wkvu, const float* __restrict__ wo,
             bf16* __restrict__ dx, bf16* __restrict__ dcat, bf16* __restrict__ dwqu,
             bf16* __restrict__ dwkvu, bf16* __restrict__ dwo)
{
  long i = (long)blockIdx.x * 256 + threadIdx.x;
  if (i < NX4) { cvt4(x, dx, i * 4, i * 4); return; }
  i -= NX4;
  if (i < NCAT4) {                 // [Wq_down(1536) ; Wkv_down(576) ; zeros(64)] x 2048
    long e = i * 4;
    long r = e >> 11;
    if (r < 1536) cvt4(wqd, dcat, e, e);
    else if (r < 2112) cvt4(wkvd, dcat, (r - 1536) * 2048 + (e & 2047), e);
    else *(uint2*)(dcat + e) = (uint2){0u, 0u};
    return;
  }
  i -= NCAT4;
  if (i < NQU4) { cvt4(wqu, dwqu, i * 4, i * 4); return; }
  i -= NQU4;
  if (i < NKVU4) { cvt4(wkvu, dwkvu, i * 4, i * 4); return; }
  i -= NKVU4;
  if (i < NWO4) { cvt4(wo, dwo, i * 4, i * 4); return; }
}

// ---------------- cos/sin table ----------------
__global__ void trig_k(const float* __restrict__ freqs, float2* __restrict__ tab)
{
  int i = blockIdx.x * 256 + threadIdx.x;
  if (i < SSD * 32) {
    float f = freqs[i];
    tab[i] = make_float2(cosf(f), sinf(f));
  }
}

// ---------------- both rmsnorms from the fused down-proj output ----------------
__global__ __launch_bounds__(256)
void rms_both(const bf16* __restrict__ Ra, const float* __restrict__ qb,
              const float* __restrict__ qw, const float* __restrict__ kvb,
              const float* __restrict__ kvw, bf16* __restrict__ qlat,
              bf16* __restrict__ kvlat)
{
  long row = blockIdx.x;
  const bf16* rp = Ra + row * NCAT;
  int tid = threadIdx.x;
  float vq[6];
  float ssq = 0.f;
#pragma unroll
  for (int i = 0; i < 6; ++i) {
    int c = tid + (i << 8);
    float x = __bfloat162float(rp[c]) + qb[c];
    vq[i] = x;
    ssq += x * x;
  }
  ssq = block_sum(ssq);
  float scq = rsqrtf(ssq / (float)QLORA + EPSF);
#pragma unroll
  for (int i = 0; i < 6; ++i) {
    int c = tid + (i << 8);
    qlat[row * QLORA + c] = __float2bfloat16(vq[i] * scq * qw[c]);
  }
  float vk[2];
  float ssk = 0.f;
#pragma unroll
  for (int i = 0; i < 2; ++i) {
    int c = tid + (i << 8);
    float x = __bfloat162float(rp[QLORA + c]) + kvb[c];
    vk[i] = x;
    ssk += x * x;
  }
  ssk = block_sum(ssk);
  float sck = rsqrtf(ssk / (float)KVLORA + EPSF);
#pragma unroll
  for (int i = 0; i < 2; ++i) {
    int c = tid + (i << 8);
    kvlat[row * KVLORA + c] = __float2bfloat16(vk[i] * sck * kvw[c]);
  }
}

// ---------------- fill Kh rope cols (broadcast over heads) ----------------
__global__ void krope_fill(const bf16* __restrict__ Ra, const float* __restrict__ kvb,
                           const float2* __restrict__ cstab, bf16* __restrict__ Kh)
{
  int idx = blockIdx.x * 256 + threadIdx.x;
  if (idx >= BSD * 32) return;
  int jp = idx & 31;
  int srow = idx >> 5;
  int s = srow & (SSD - 1), bb = srow >> 11;
  float x0 = __bfloat162float(Ra[(long)srow * NCAT + 2048 + 2 * jp]) + kvb[512 + 2 * jp];
  float x1 = __bfloat162float(Ra[(long)srow * NCAT + 2049 + 2 * jp]) + kvb[513 + 2 * jp];
  float2 cs = cstab[s * 32 + jp];
  union { bf16 h2[2]; unsigned u; } pk;
  pk.h2[0] = __float2bfloat16(x0 * cs.x - x1 * cs.y);
  pk.h2[1] = __float2bfloat16(x0 * cs.y + x1 * cs.x);
#pragma unroll
  for (int h = 0; h < NHD; ++h)
    *(unsigned*)&Kh[((long)(bb * NHD + h) * SSD + s) * QKD + 128 + 2 * jp] = pk.u;
}

// ---------------- build V^T: kvf(B,S,NH*128) -> Vt (BH,128,S) ----------------
__global__ __launch_bounds__(256)
void build_vt(const bf16* __restrict__ kvf, bf16* __restrict__ Vt)
{
  __shared__ float t[32][33];
  int s0 = blockIdx.x * 32, d0 = blockIdx.y * 32, z = blockIdx.z;
  int b = z / NHD, h = z % NHD;
  int tx = threadIdx.x, ty = threadIdx.y;  // 32 x 8
#pragma unroll
  for (int r = 0; r < 4; ++r) {
    int sl = ty + r * 8;
    t[sl][tx] = __bfloat162float(kvf[(long)(b * SSD + s0 + sl) * 2048 + h * 128 + d0 + tx]);
  }
  __syncthreads();
#pragma unroll
  for (int r = 0; r < 4; ++r) {
    int dl = ty + r * 8;
    Vt[((long)z * 128 + d0 + dl) * SSD + s0 + tx] = __float2bfloat16(t[tx][dl]);
  }
}

// ---------------- diagnostic: ws too small ----------------
__global__ void diag_fill(float* out) { out[blockIdx.x * 256 + threadIdx.x] = 1000.0f; }

extern "C" void kernel_launch(void* const* d_in, const int* in_sizes, int n_in,
                              void* d_out, int out_size, void* d_ws, size_t ws_size,
                              hipStream_t stream)
{
  const float* x     = (const float*)d_in[0];
  const float* freqs = (const float*)d_in[1];
  const float* Wqd   = (const float*)d_in[3];
  const float* Wqdb  = (const float*)d_in[4];
  const float* qnw   = (const float*)d_in[5];
  const float* Wqu   = (const float*)d_in[6];
  const float* Wqub  = (const float*)d_in[7];
  const float* Wkvd  = (const float*)d_in[8];
  const float* Wkvdb = (const float*)d_in[9];
  const float* kvnw  = (const float*)d_in[10];
  const float* Wkvu  = (const float*)d_in[11];
  const float* Wkvub = (const float*)d_in[12];
  const float* Wo    = (const float*)d_in[13];
  const float* Wob   = (const float*)d_in[14];
  float* out = (float*)d_out;

  char* ws = (char*)d_ws;
  size_t off = 0;
  auto alloc = [&](size_t bytes) {
    void* p = ws + off;
    off += (bytes + 255) & ~(size_t)255;
    return p;
  };

  bf16* Wcat16 = (bf16*)alloc((size_t)NCAT * DIMD * 2);
  bf16* Wqu16  = (bf16*)alloc((size_t)3072 * QLORA * 2);
  bf16* Wkvu16 = (bf16*)alloc((size_t)4096 * KVLORA * 2);
  bf16* Wo16   = (bf16*)alloc((size_t)DIMD * 2048 * 2);
  bf16* x16    = (bf16*)alloc((size_t)BSD * DIMD * 2);
  bf16* Ra     = (bf16*)alloc((size_t)BSD * NCAT * 2);     // fused down-proj out
  bf16* qlat   = (bf16*)alloc((size_t)BSD * QLORA * 2);
  bf16* kvlat  = (bf16*)alloc((size_t)BSD * KVLORA * 2);
  bf16* kvf    = (bf16*)alloc((size_t)BSD * 2048 * 2);     // V-part; reused as attnall
  bf16* Qh16   = (bf16*)alloc((size_t)BHN * SSD * QKD * 2);
  bf16* Kh16   = (bf16*)alloc((size_t)BHN * SSD * QKD * 2);
  bf16* Vt16   = (bf16*)alloc((size_t)BHN * 128 * SSD * 2);
  float2* cstab = (float2*)alloc((size_t)SSD * 32 * sizeof(float2));

  bf16* attnall = kvf;   // kvf dead after build_vt; flash writes attnall after

  if (off > ws_size) { diag_fill<<<8, 256, 0, stream>>>(out); return; }

  dim3 blk(256);
  auto cdiv = [](long a, long b) { return (int)((a + b - 1) / b); };

  // 1-2: converts + trig table
  long tot4 = NX4 + NCAT4 + NQU4 + NKVU4 + NWO4;
  cvt_all<<<cdiv(tot4, 256), blk, 0, stream>>>(x, Wqd, Wkvd, Wqu, Wkvu, Wo,
                                               x16, Wcat16, Wqu16, Wkvu16, Wo16);
  trig_k<<<cdiv((long)SSD * 32, 256), blk, 0, stream>>>(freqs, cstab);

  // 3: fused Q-down + KV-down GEMM  (N = 2176)
  gemm_bt<1><<<dim3(NCAT / 128, BSD / 128), blk, 0, stream>>>(
      x16, Wcat16, nullptr, Ra, nullptr, nullptr, BSD, NCAT, DIMD, NCAT);

  // 4: both rmsnorms (down-proj biases folded in)
  rms_both<<<BSD, blk, 0, stream>>>(Ra, Wqdb, qnw, Wkvdb, kvnw, qlat, kvlat);

  // 5: Q-up GEMM with fused rope -> Qh
  gemm_bt<2><<<dim3(3072 / 128, BSD / 128), blk, 0, stream>>>(
      qlat, Wqu16, Wqub, Qh16, nullptr, cstab, BSD, 3072, QLORA, 0);

  // 6: KV-up GEMM with fused split -> Kh(nope) + kvf(V)
  gemm_bt<3><<<dim3(4096 / 128, BSD / 128), blk, 0, stream>>>(
      kvlat, Wkvu16, Wkvub, Kh16, kvf, nullptr, BSD, 4096, KVLORA, 0);

  // 7: Kh rope cols (broadcast over heads)
  krope_fill<<<cdiv((long)BSD * 32, 256), blk, 0, stream>>>(Ra, Wkvdb, cstab, Kh16);

  // 8: V^T
  build_vt<<<dim3(SSD / 32, 128 / 32, BHN), dim3(32, 8), 0, stream>>>(kvf, Vt16);

  // 9: flash attention -> attnall (B,S,NH*128)
  flash_attn<<<dim3(16, BHN), blk, 0, stream>>>(Qh16, Kh16, Vt16, attnall);

  // 10: output projection (fp32 out)
  gemm_bt<0><<<dim3(2048 / 128, BSD / 128), blk, 0, stream>>>(
      attnall, Wo16, Wob, out, nullptr, nullptr, BSD, DIMD, 2048, DIMD);
}